// Round 1
// baseline (163.774 us; speedup 1.0000x reference)
//
#include <hip/hip_runtime.h>

#define B_ 16
#define N_ 1024
#define DIN 256
#define K_ 24
#define D_ 128
#define KD_ 3072
#define NSPLIT 16
#define NCHUNK 64   /* N_/NSPLIT */
#define EPS_ 1e-7f

// ---------------- K1: partial t[b,k,i] = sum_n c[b,k,n]*u[b,n,i] over an n-chunk
__global__ __launch_bounds__(256) void k_tpart(const float* __restrict__ u,
                                               const float* __restrict__ c,
                                               float* __restrict__ tpart,
                                               int uniform) {
    const int b = blockIdx.y, s = blockIdx.x, i = threadIdx.x;
    __shared__ float c_lds[K_][NCHUNK];
    const float* up = u + ((size_t)(b * N_ + s * NCHUNK)) * DIN + i;
    float* tp = tpart + ((size_t)((b * NSPLIT + s) * K_)) * DIN + i;

    if (uniform) {
        // c == 1/24 for all k: single accumulator, broadcast to all k slots
        float a = 0.f;
        #pragma unroll 4
        for (int n = 0; n < NCHUNK; ++n) a += up[(size_t)n * DIN];
        a *= (1.0f / 24.0f);
        for (int k = 0; k < K_; ++k) tp[(size_t)k * DIN] = a;
    } else {
        for (int idx = threadIdx.x; idx < K_ * NCHUNK; idx += 256) {
            int k = idx / NCHUNK, n = idx % NCHUNK;
            c_lds[k][n] = c[((size_t)(b * K_ + k)) * N_ + s * NCHUNK + n];
        }
        __syncthreads();
        float acc[K_];
        #pragma unroll
        for (int k = 0; k < K_; ++k) acc[k] = 0.f;
        for (int n = 0; n < NCHUNK; ++n) {
            float uv = up[(size_t)n * DIN];
            #pragma unroll
            for (int k = 0; k < K_; ++k) acc[k] += c_lds[k][n] * uv;
        }
        #pragma unroll
        for (int k = 0; k < K_; ++k) tp[(size_t)k * DIN] = acc[k];
    }
}

// ---------------- K2: t-reduce, s = t@W_k, v = squash(s), w2 = v@W_k^T
__global__ __launch_bounds__(128) void k_sv(const float* __restrict__ tpart,
                                            const float* __restrict__ W,
                                            float* __restrict__ w2,
                                            float* __restrict__ outv,
                                            int last) {
    const int b = blockIdx.y, k = blockIdx.x, d = threadIdx.x;
    __shared__ float t_lds[DIN];
    __shared__ float v_lds[D_];
    __shared__ float red[2];

    // reduce the NSPLIT partials of t[b,k,:]
    for (int i = d; i < DIN; i += D_) {
        float a = 0.f;
        #pragma unroll
        for (int s = 0; s < NSPLIT; ++s)
            a += tpart[((size_t)((b * NSPLIT + s) * K_ + k)) * DIN + i];
        t_lds[i] = a;
    }
    __syncthreads();

    // s_d = sum_i t[i] * W[i, k*128+d]
    float sd = 0.f;
    const float* Wp = W + (size_t)k * D_ + d;
    #pragma unroll 8
    for (int i = 0; i < DIN; ++i) sd += t_lds[i] * Wp[(size_t)i * KD_];

    // squash: v = s * rsqrt(sum(s^2) + eps)
    float sq = sd * sd;
    #pragma unroll
    for (int m = 1; m < 64; m <<= 1) sq += __shfl_xor(sq, m);
    const int lane = threadIdx.x & 63, wv = threadIdx.x >> 6;
    if (lane == 0) red[wv] = sq;
    __syncthreads();
    const float nrm = red[0] + red[1];
    const float inv = rsqrtf(nrm + EPS_);
    const float vd = sd * inv;
    v_lds[d] = vd;
    if (last) outv[((size_t)(b * K_ + k)) * D_ + d] = vd;
    __syncthreads();

    if (!last) {
        // w2[i] = sum_d v[d] * W[i, k*128+d]
        for (int i = d; i < DIN; i += D_) {
            const float* Wp2 = W + (size_t)i * KD_ + (size_t)k * D_;
            float a = 0.f;
            #pragma unroll 8
            for (int dd = 0; dd < D_; ++dd) a += v_lds[dd] * Wp2[dd];
            w2[((size_t)(b * K_ + k)) * DIN + i] = a;
        }
    }
}

// ---------------- K3: b[b,k,n] = sum_i u[b,n,i]*w2[b,k,i]; softmax over k -> c
__global__ __launch_bounds__(128) void k_bsoft(const float* __restrict__ u,
                                               const float* __restrict__ w2,
                                               float* __restrict__ c) {
    const int b = blockIdx.y;
    const int n = blockIdx.x * 128 + threadIdx.x;
    __shared__ float w2_lds[K_ * DIN];  // 24 KB
    for (int idx = threadIdx.x; idx < K_ * DIN; idx += 128)
        w2_lds[idx] = w2[(size_t)b * K_ * DIN + idx];
    __syncthreads();

    const float4* up = (const float4*)(u + ((size_t)(b * N_ + n)) * DIN);
    float acc[K_];
    #pragma unroll
    for (int k = 0; k < K_; ++k) acc[k] = 0.f;

    for (int i4 = 0; i4 < DIN / 4; ++i4) {
        float4 uv = up[i4];
        #pragma unroll
        for (int k = 0; k < K_; ++k) {
            const float* wr = &w2_lds[k * DIN + i4 * 4];
            acc[k] += uv.x * wr[0] + uv.y * wr[1] + uv.z * wr[2] + uv.w * wr[3];
        }
    }

    // softmax over k (24 logits in registers)
    float mx = -1e30f;
    #pragma unroll
    for (int k = 0; k < K_; ++k) mx = fmaxf(mx, acc[k]);
    float sum = 0.f;
    #pragma unroll
    for (int k = 0; k < K_; ++k) { acc[k] = __expf(acc[k] - mx); sum += acc[k]; }
    const float inv = 1.f / sum;
    #pragma unroll
    for (int k = 0; k < K_; ++k)
        c[((size_t)(b * K_ + k)) * N_ + n] = acc[k] * inv;
}

extern "C" void kernel_launch(void* const* d_in, const int* in_sizes, int n_in,
                              void* d_out, int out_size, void* d_ws, size_t ws_size,
                              hipStream_t stream) {
    const float* u = (const float*)d_in[0];   // [16,1024,256]
    const float* W = (const float*)d_in[1];   // [256,3072]
    float* out = (float*)d_out;               // [16,24,128]

    char* ws = (char*)d_ws;
    float* tpart = (float*)ws;                                  // 6,291,456 B
    float* c     = (float*)(ws + 6291456);                      // 1,572,864 B
    float* w2    = (float*)(ws + 6291456 + 1572864);            //   393,216 B

    dim3 g1(NSPLIT, B_), t1(256);
    dim3 g2(K_, B_),     t2(128);
    dim3 g3(N_ / 128, B_), t3(128);

    // ---- iteration 0 (b=0 -> c uniform = 1/24)
    k_tpart<<<g1, t1, 0, stream>>>(u, nullptr, tpart, 1);
    k_sv   <<<g2, t2, 0, stream>>>(tpart, W, w2, out, 0);
    k_bsoft<<<g3, t3, 0, stream>>>(u, w2, c);
    // ---- iteration 1
    k_tpart<<<g1, t1, 0, stream>>>(u, c, tpart, 0);
    k_sv   <<<g2, t2, 0, stream>>>(tpart, W, w2, out, 0);
    k_bsoft<<<g3, t3, 0, stream>>>(u, w2, c);
    // ---- iteration 2 (no b-update needed)
    k_tpart<<<g1, t1, 0, stream>>>(u, c, tpart, 0);
    k_sv   <<<g2, t2, 0, stream>>>(tpart, W, w2, out, 1);
}

// Round 2
// 130.609 us; speedup vs baseline: 1.2539x; 1.2539x over previous
//
#include <hip/hip_runtime.h>

#define B_ 16
#define N_ 1024
#define DIN 256
#define K_ 24
#define D_ 128
#define KD_ 3072
#define NSPLIT 16
#define NCHUNK 64
#define EPS_ 1e-7f

// ---------------- K0: column-sum partials (iteration-0 t, c uniform)
__global__ __launch_bounds__(256) void k_colsum(const float* __restrict__ u,
                                                float* __restrict__ tupart) {
    const int b = blockIdx.y, s = blockIdx.x, i = threadIdx.x;
    const float* up = u + ((size_t)(b * N_ + s * NCHUNK)) * DIN + i;
    float a0 = 0.f, a1 = 0.f, a2 = 0.f, a3 = 0.f;
    #pragma unroll
    for (int n = 0; n < NCHUNK; n += 4) {
        a0 += up[(size_t)n * DIN];
        a1 += up[(size_t)(n + 1) * DIN];
        a2 += up[(size_t)(n + 2) * DIN];
        a3 += up[(size_t)(n + 3) * DIN];
    }
    tupart[((size_t)(b * NSPLIT + s)) * DIN + i] = (a0 + a1) + (a2 + a3);
}

// ---------------- K2: t-reduce, s = t@W_k, v = squash(s), w2 = v@W_k^T
// mode 0: first iter (read tupart, scale 1/24), 1: mid, 2: last (write out only)
__global__ __launch_bounds__(256) void k_sv(const float* __restrict__ tpart,
                                            const float* __restrict__ tupart,
                                            const float* __restrict__ W,
                                            float* __restrict__ w2,
                                            float* __restrict__ outv,
                                            int mode) {
    const int b = blockIdx.y, k = blockIdx.x, t = threadIdx.x;
    __shared__ float t_lds[DIN];
    __shared__ float sred[2][D_];
    __shared__ __align__(16) float v_lds[D_];
    __shared__ float red2[2];

    // reduce partials of t[b,k,:]
    {
        float a = 0.f;
        if (mode == 0) {
            #pragma unroll
            for (int s = 0; s < NSPLIT; ++s)
                a += tupart[((size_t)(b * NSPLIT + s)) * DIN + t];
            a *= (1.0f / 24.0f);
        } else {
            #pragma unroll
            for (int s = 0; s < NSPLIT; ++s)
                a += tpart[((size_t)((b * NSPLIT + s) * K_ + k)) * DIN + t];
        }
        t_lds[t] = a;
    }
    __syncthreads();

    // s_d = sum_i t[i]*W[i,k*128+d], split i over 2 halves
    const int d = t & (D_ - 1), h = t >> 7;
    float sd = 0.f;
    {
        const float* Wp = W + (size_t)(h * 128) * KD_ + (size_t)k * D_ + d;
        const float* tp = t_lds + h * 128;
        #pragma unroll 8
        for (int i = 0; i < 128; ++i) sd += tp[i] * Wp[(size_t)i * KD_];
    }
    sred[h][d] = sd;
    __syncthreads();
    if (t < D_) {
        sd = sred[0][d] + sred[1][d];
        float sq = sd * sd;
        #pragma unroll
        for (int m = 1; m < 64; m <<= 1) sq += __shfl_xor(sq, m);
        if ((t & 63) == 0) red2[t >> 6] = sq;
    }
    __syncthreads();
    const float nrm = red2[0] + red2[1];
    const float inv = rsqrtf(nrm + EPS_);
    if (t < D_) {
        const float vd = sd * inv;
        v_lds[d] = vd;
        if (mode == 2) outv[((size_t)(b * K_ + k)) * D_ + d] = vd;
    }
    __syncthreads();

    if (mode != 2) {
        // w2[i] = sum_d v[d]*W[i,k*128+d], i = t, float4 over d
        const float4* Wq = (const float4*)(W + (size_t)t * KD_ + (size_t)k * D_);
        const float4* vq = (const float4*)v_lds;
        float a = 0.f;
        #pragma unroll 8
        for (int q = 0; q < 32; ++q) {
            float4 wv = Wq[q], vv = vq[q];
            a += wv.x * vv.x + wv.y * vv.y + wv.z * vv.z + wv.w * vv.w;
        }
        w2[((size_t)(b * K_ + k)) * DIN + t] = a;
    }
}

// ---------------- F: fused logits + softmax + t-partial for one 64-n chunk
__global__ __launch_bounds__(512) void k_fused(const float* __restrict__ u,
                                               const float* __restrict__ w2,
                                               float* __restrict__ tpart) {
    const int b = blockIdx.y, s = blockIdx.x, t = threadIdx.x;
    __shared__ float u_lds[NCHUNK * 257];                 // 65,792 B, pad 257
    __shared__ __align__(16) float Rbuf[12800];           // 51,200 B (scratch, then buf)
    __shared__ __align__(16) float c_lds[NCHUNK * 32];    // 8,192 B

    // stage u chunk (64 x 256) into LDS
    {
        const float4* ug = (const float4*)(u + ((size_t)(b * N_ + s * NCHUNK)) * DIN);
        for (int idx = t; idx < NCHUNK * 64; idx += 512) {
            const int n = idx >> 6, q = idx & 63;
            float4 v = ug[(size_t)n * 64 + q];
            float* dst = u_lds + n * 257 + q * 4;
            dst[0] = v.x; dst[1] = v.y; dst[2] = v.z; dst[3] = v.w;
        }
    }
    __syncthreads();

    // phase 1: partial logits b[n,k] = sum_i u[n,i]*w2[k,i]
    const float* w2g = w2 + (size_t)b * K_ * DIN;
    {
        const int npair = t & 31, ipart = t >> 5;   // 2 n per thread, 16 i per ipart
        const int n0 = npair * 2, i0 = ipart * 16;
        float acc[2][K_];
        #pragma unroll
        for (int j = 0; j < 2; ++j)
            #pragma unroll
            for (int k = 0; k < K_; ++k) acc[j][k] = 0.f;
        #pragma unroll
        for (int g = 0; g < 4; ++g) {
            float ua[2][4];
            #pragma unroll
            for (int j = 0; j < 2; ++j)
                #pragma unroll
                for (int m = 0; m < 4; ++m)
                    ua[j][m] = u_lds[(n0 + j) * 257 + i0 + g * 4 + m];
            #pragma unroll
            for (int k = 0; k < K_; ++k) {
                const float4 wq = *(const float4*)(w2g + k * DIN + i0 + g * 4);
                #pragma unroll
                for (int j = 0; j < 2; ++j)
                    acc[j][k] += ua[j][0] * wq.x + ua[j][1] * wq.y +
                                 ua[j][2] * wq.z + ua[j][3] * wq.w;
            }
        }
        // reduce the two iparts of this wave (lanes q <-> q+32 share npair)
        #pragma unroll
        for (int j = 0; j < 2; ++j)
            #pragma unroll
            for (int k = 0; k < K_; ++k)
                acc[j][k] += __shfl_xor(acc[j][k], 32);
        const int w = t >> 6;
        const int j = ((t & 63) >= 32) ? 1 : 0;
        float* sc = Rbuf + (w * NCHUNK + n0 + j) * 25;
        #pragma unroll
        for (int k = 0; k < K_; ++k) sc[k] = acc[j][k];
    }
    __syncthreads();

    // phase 1b+2: reduce 8 wave-partials, softmax over k (8-lane groups, 3 k each)
    {
        const int n = t >> 3, kq = t & 7;
        float lg[3];
        #pragma unroll
        for (int j = 0; j < 3; ++j) {
            float a = 0.f;
            #pragma unroll
            for (int w = 0; w < 8; ++w) a += Rbuf[(w * NCHUNK + n) * 25 + kq * 3 + j];
            lg[j] = a;
        }
        float mx = fmaxf(fmaxf(lg[0], lg[1]), lg[2]);
        #pragma unroll
        for (int m = 1; m < 8; m <<= 1) mx = fmaxf(mx, __shfl_xor(mx, m));
        float e0 = __expf(lg[0] - mx), e1 = __expf(lg[1] - mx), e2 = __expf(lg[2] - mx);
        float sm = e0 + e1 + e2;
        #pragma unroll
        for (int m = 1; m < 8; m <<= 1) sm += __shfl_xor(sm, m);
        const float inv = 1.0f / sm;
        c_lds[n * 32 + kq * 3 + 0] = e0 * inv;
        c_lds[n * 32 + kq * 3 + 1] = e1 * inv;
        c_lds[n * 32 + kq * 3 + 2] = e2 * inv;
    }
    __syncthreads();

    // phase 3: tpart[k][i] = sum_n c[n][k]*u[n][i], i-parallel, n split in 2 halves
    {
        const int i = t & 255, nh = t >> 8;
        float acc[K_];
        #pragma unroll
        for (int k = 0; k < K_; ++k) acc[k] = 0.f;
        #pragma unroll 4
        for (int n = nh * 32; n < nh * 32 + 32; ++n) {
            const float uv = u_lds[n * 257 + i];
            const float4* cq = (const float4*)(c_lds + n * 32);
            #pragma unroll
            for (int q = 0; q < 6; ++q) {
                float4 cv = cq[q];
                acc[q * 4 + 0] += uv * cv.x;
                acc[q * 4 + 1] += uv * cv.y;
                acc[q * 4 + 2] += uv * cv.z;
                acc[q * 4 + 3] += uv * cv.w;
            }
        }
        __syncthreads();
        if (nh == 1) {
            #pragma unroll
            for (int k = 0; k < K_; ++k) Rbuf[k * 257 + i] = acc[k];
        }
        __syncthreads();
        if (nh == 0) {
            float* tp = tpart + ((size_t)((b * NSPLIT + s) * K_)) * DIN + i;
            #pragma unroll
            for (int k = 0; k < K_; ++k) tp[(size_t)k * DIN] = acc[k] + Rbuf[k * 257 + i];
        }
    }
}

extern "C" void kernel_launch(void* const* d_in, const int* in_sizes, int n_in,
                              void* d_out, int out_size, void* d_ws, size_t ws_size,
                              hipStream_t stream) {
    const float* u = (const float*)d_in[0];   // [16,1024,256]
    const float* W = (const float*)d_in[1];   // [256,3072]
    float* out = (float*)d_out;               // [16,24,128]

    char* ws = (char*)d_ws;
    float* tpart  = (float*)ws;                              // 6,291,456 B
    float* w2     = (float*)(ws + 6291456);                  //   393,216 B
    float* tupart = (float*)(ws + 6291456 + 393216);         //   262,144 B

    dim3 gc(NSPLIT, B_), tc(256);
    dim3 gs(K_, B_),     ts(256);
    dim3 gf(NSPLIT, B_), tf(512);

    // iter 0 (c uniform = 1/24)
    k_colsum<<<gc, tc, 0, stream>>>(u, tupart);
    k_sv    <<<gs, ts, 0, stream>>>(tpart, tupart, W, w2, out, 0);
    // iter 1
    k_fused <<<gf, tf, 0, stream>>>(u, w2, tpart);
    k_sv    <<<gs, ts, 0, stream>>>(tpart, tupart, W, w2, out, 1);
    // iter 2
    k_fused <<<gf, tf, 0, stream>>>(u, w2, tpart);
    k_sv    <<<gs, ts, 0, stream>>>(tpart, tupart, W, w2, out, 2);
}

// Round 3
// 81.694 us; speedup vs baseline: 2.0047x; 1.5988x over previous
//
#include <hip/hip_runtime.h>

#define B_ 16
#define N_ 1024
#define DIN 256
#define K_ 24
#define D_ 128
#define KD_ 3072
#define NSPLIT 16
#define NCHUNK 64
#define EPS_ 1e-7f

// ---------------- K0: column-sum partials (iteration-0 t, c uniform)
__global__ __launch_bounds__(256) void k_colsum(const float* __restrict__ u,
                                                float* __restrict__ tupart) {
    const int b = blockIdx.y, s = blockIdx.x, i = threadIdx.x;
    const float* up = u + ((size_t)(b * N_ + s * NCHUNK)) * DIN + i;
    float a0 = 0.f, a1 = 0.f, a2 = 0.f, a3 = 0.f;
    #pragma unroll
    for (int n = 0; n < NCHUNK; n += 4) {
        a0 += up[(size_t)n * DIN];
        a1 += up[(size_t)(n + 1) * DIN];
        a2 += up[(size_t)(n + 2) * DIN];
        a3 += up[(size_t)(n + 3) * DIN];
    }
    tupart[((size_t)(b * NSPLIT + s)) * DIN + i] = (a0 + a1) + (a2 + a3);
}

// ---------------- K2: t-reduce, s = t@W_k, v = squash(s), w2 = v@W_k^T
// mode 0: first iter (read tupart, scale 1/24), 1: mid, 2: last (write out only)
__global__ __launch_bounds__(256) void k_sv(const float* __restrict__ tpart,
                                            const float* __restrict__ tupart,
                                            const float* __restrict__ W,
                                            float* __restrict__ w2,
                                            float* __restrict__ outv,
                                            int mode) {
    const int b = blockIdx.y, k = blockIdx.x, t = threadIdx.x;
    __shared__ float t_lds[DIN];
    __shared__ float sred[2][D_];
    __shared__ __align__(16) float v_lds[D_];
    __shared__ float red2[2];

    // reduce partials of t[b,k,:]
    {
        float a = 0.f;
        if (mode == 0) {
            #pragma unroll
            for (int s = 0; s < NSPLIT; ++s)
                a += tupart[((size_t)(b * NSPLIT + s)) * DIN + t];
            a *= (1.0f / 24.0f);
        } else {
            #pragma unroll
            for (int s = 0; s < NSPLIT; ++s)
                a += tpart[((size_t)((b * NSPLIT + s) * K_ + k)) * DIN + t];
        }
        t_lds[t] = a;
    }
    __syncthreads();

    // s_d = sum_i t[i]*W[i,k*128+d], split i over 2 halves
    const int d = t & (D_ - 1), h = t >> 7;
    float sd = 0.f;
    {
        const float* Wp = W + (size_t)(h * 128) * KD_ + (size_t)k * D_ + d;
        const float* tp = t_lds + h * 128;
        #pragma unroll 8
        for (int i = 0; i < 128; ++i) sd += tp[i] * Wp[(size_t)i * KD_];
    }
    sred[h][d] = sd;
    __syncthreads();
    if (t < D_) {
        sd = sred[0][d] + sred[1][d];
        float sq = sd * sd;
        #pragma unroll
        for (int m = 1; m < 64; m <<= 1) sq += __shfl_xor(sq, m);
        if ((t & 63) == 0) red2[t >> 6] = sq;
    }
    __syncthreads();
    const float nrm = red2[0] + red2[1];
    const float inv = rsqrtf(nrm + EPS_);
    if (t < D_) {
        const float vd = sd * inv;
        v_lds[d] = vd;
        if (mode == 2) outv[((size_t)(b * K_ + k)) * D_ + d] = vd;
    }
    __syncthreads();

    if (mode != 2) {
        // w2[i] = sum_d v[d]*W[i,k*128+d], i = t, float4 over d
        const float4* Wq = (const float4*)(W + (size_t)t * KD_ + (size_t)k * D_);
        const float4* vq = (const float4*)v_lds;
        float a = 0.f;
        #pragma unroll 8
        for (int q = 0; q < 32; ++q) {
            float4 wv = Wq[q], vv = vq[q];
            a += wv.x * vv.x + wv.y * vv.y + wv.z * vv.z + wv.w * vv.w;
        }
        w2[((size_t)(b * K_ + k)) * DIN + t] = a;
    }
}

// ---------------- F: fused logits + softmax + t-partial for one 64-n chunk
__global__ __launch_bounds__(512) void k_fused(const float* __restrict__ u,
                                               const float* __restrict__ w2,
                                               float* __restrict__ tpart) {
    const int b = blockIdx.y, s = blockIdx.x, t = threadIdx.x;
    __shared__ float u_lds[NCHUNK * 257];                 // 65,792 B, pad 257
    __shared__ __align__(16) float Rbuf[12800];           // 51,200 B (scratch, then buf)
    __shared__ __align__(16) float c_lds[NCHUNK * 32];    // 8,192 B

    // stage u chunk (64 x 256) into LDS
    {
        const float4* ug = (const float4*)(u + ((size_t)(b * N_ + s * NCHUNK)) * DIN);
        for (int idx = t; idx < NCHUNK * 64; idx += 512) {
            const int n = idx >> 6, q = idx & 63;
            float4 v = ug[(size_t)n * 64 + q];
            float* dst = u_lds + n * 257 + q * 4;
            dst[0] = v.x; dst[1] = v.y; dst[2] = v.z; dst[3] = v.w;
        }
    }
    __syncthreads();

    // phase 1: partial logits b[n,k] = sum_i u[n,i]*w2[k,i]
    // NOTE: acc0/acc1 statically indexed everywhere (runtime-indexed register
    // arrays get demoted to scratch -> 100+ MB of local-memory traffic).
    const float* w2g = w2 + (size_t)b * K_ * DIN;
    {
        const int npair = t & 31, ipart = t >> 5;   // 2 n per thread, 16 i per ipart
        const int n0 = npair * 2, i0 = ipart * 16;
        float acc0[K_], acc1[K_];
        #pragma unroll
        for (int k = 0; k < K_; ++k) { acc0[k] = 0.f; acc1[k] = 0.f; }
        #pragma unroll
        for (int g = 0; g < 4; ++g) {
            float ua0[4], ua1[4];
            #pragma unroll
            for (int m = 0; m < 4; ++m) {
                ua0[m] = u_lds[(n0 + 0) * 257 + i0 + g * 4 + m];
                ua1[m] = u_lds[(n0 + 1) * 257 + i0 + g * 4 + m];
            }
            #pragma unroll
            for (int k = 0; k < K_; ++k) {
                const float4 wq = *(const float4*)(w2g + k * DIN + i0 + g * 4);
                acc0[k] += ua0[0] * wq.x + ua0[1] * wq.y + ua0[2] * wq.z + ua0[3] * wq.w;
                acc1[k] += ua1[0] * wq.x + ua1[1] * wq.y + ua1[2] * wq.z + ua1[3] * wq.w;
            }
        }
        // reduce the two iparts of this wave (lanes q <-> q+32 share npair)
        #pragma unroll
        for (int k = 0; k < K_; ++k) {
            acc0[k] += __shfl_xor(acc0[k], 32);
            acc1[k] += __shfl_xor(acc1[k], 32);
        }
        const int w = t >> 6;
        const int hi = (t & 63) >= 32;
        float* sc = Rbuf + (w * NCHUNK + n0 + (hi ? 1 : 0)) * 25;
        #pragma unroll
        for (int k = 0; k < K_; ++k) sc[k] = hi ? acc1[k] : acc0[k];
    }
    __syncthreads();

    // phase 1b+2: reduce 8 wave-partials, softmax over k (8-lane groups, 3 k each)
    {
        const int n = t >> 3, kq = t & 7;
        float lg[3];
        #pragma unroll
        for (int j = 0; j < 3; ++j) {
            float a = 0.f;
            #pragma unroll
            for (int w = 0; w < 8; ++w) a += Rbuf[(w * NCHUNK + n) * 25 + kq * 3 + j];
            lg[j] = a;
        }
        float mx = fmaxf(fmaxf(lg[0], lg[1]), lg[2]);
        #pragma unroll
        for (int m = 1; m < 8; m <<= 1) mx = fmaxf(mx, __shfl_xor(mx, m));
        float e0 = __expf(lg[0] - mx), e1 = __expf(lg[1] - mx), e2 = __expf(lg[2] - mx);
        float sm = e0 + e1 + e2;
        #pragma unroll
        for (int m = 1; m < 8; m <<= 1) sm += __shfl_xor(sm, m);
        const float inv = 1.0f / sm;
        c_lds[n * 32 + kq * 3 + 0] = e0 * inv;
        c_lds[n * 32 + kq * 3 + 1] = e1 * inv;
        c_lds[n * 32 + kq * 3 + 2] = e2 * inv;
    }
    __syncthreads();

    // phase 3: tpart[k][i] = sum_n c[n][k]*u[n][i], i-parallel, n split in 2 halves
    {
        const int i = t & 255, nh = t >> 8;
        float acc[K_];
        #pragma unroll
        for (int k = 0; k < K_; ++k) acc[k] = 0.f;
        #pragma unroll 4
        for (int n = nh * 32; n < nh * 32 + 32; ++n) {
            const float uv = u_lds[n * 257 + i];
            const float4* cq = (const float4*)(c_lds + n * 32);
            #pragma unroll
            for (int q = 0; q < 6; ++q) {
                float4 cv = cq[q];
                acc[q * 4 + 0] += uv * cv.x;
                acc[q * 4 + 1] += uv * cv.y;
                acc[q * 4 + 2] += uv * cv.z;
                acc[q * 4 + 3] += uv * cv.w;
            }
        }
        __syncthreads();
        if (nh == 1) {
            #pragma unroll
            for (int k = 0; k < K_; ++k) Rbuf[k * 257 + i] = acc[k];
        }
        __syncthreads();
        if (nh == 0) {
            float* tp = tpart + ((size_t)((b * NSPLIT + s) * K_)) * DIN + i;
            #pragma unroll
            for (int k = 0; k < K_; ++k) tp[(size_t)k * DIN] = acc[k] + Rbuf[k * 257 + i];
        }
    }
}

extern "C" void kernel_launch(void* const* d_in, const int* in_sizes, int n_in,
                              void* d_out, int out_size, void* d_ws, size_t ws_size,
                              hipStream_t stream) {
    const float* u = (const float*)d_in[0];   // [16,1024,256]
    const float* W = (const float*)d_in[1];   // [256,3072]
    float* out = (float*)d_out;               // [16,24,128]

    char* ws = (char*)d_ws;
    float* tpart  = (float*)ws;                              // 6,291,456 B
    float* w2     = (float*)(ws + 6291456);                  //   393,216 B
    float* tupart = (float*)(ws + 6291456 + 393216);         //   262,144 B

    dim3 gc(NSPLIT, B_), tc(256);
    dim3 gs(K_, B_),     ts(256);
    dim3 gf(NSPLIT, B_), tf(512);

    // iter 0 (c uniform = 1/24)
    k_colsum<<<gc, tc, 0, stream>>>(u, tupart);
    k_sv    <<<gs, ts, 0, stream>>>(tpart, tupart, W, w2, out, 0);
    // iter 1
    k_fused <<<gf, tf, 0, stream>>>(u, w2, tpart);
    k_sv    <<<gs, ts, 0, stream>>>(tpart, tupart, W, w2, out, 1);
    // iter 2
    k_fused <<<gf, tf, 0, stream>>>(u, w2, tpart);
    k_sv    <<<gs, ts, 0, stream>>>(tpart, tupart, W, w2, out, 2);
}